// Round 8
// baseline (2208.634 us; speedup 1.0000x reference)
//
#include <hip/hip_runtime.h>
#include <hip/hip_bf16.h>
#include <math.h>

// Problem constants (from reference): N=50000, D=64, E=800000, H=64
#define DFEAT 64

typedef unsigned int u32;
typedef unsigned short u16;

// bf16(hi 16 bits of f32) -> f32, exact
__device__ inline float bflo(u32 u) { return __uint_as_float(u << 16); }
__device__ inline float bfhi(u32 u) { return __uint_as_float(u & 0xffff0000u); }

// ---------------- count in-degree (int atomics, cheap) ----------------
__global__ void count_edges_k(const int* __restrict__ rows, int E, int* __restrict__ cnt) {
    int e = blockIdx.x * blockDim.x + threadIdx.x;
    if (e < E) atomicAdd(&cnt[rows[e]], 1);
}

// ---------------- exclusive scan of counts -> CSR offsets + cursor ----------------
__global__ __launch_bounds__(1024) void scan_k(const int* __restrict__ cnt_all, int n,
                                               int* __restrict__ offs_all, int* __restrict__ cur_all) {
    const int* cnt = cnt_all + (size_t)blockIdx.x * n;
    int* offs = offs_all + (size_t)blockIdx.x * (n + 1);
    int* cur  = cur_all  + (size_t)blockIdx.x * n;

    __shared__ int lsum[1024];
    int tid = threadIdx.x;
    int per = (n + 1023) / 1024;
    int start = tid * per;
    int s = 0;
    for (int j = 0; j < per; ++j) {
        int i = start + j;
        if (i < n) s += cnt[i];
    }
    lsum[tid] = s;
    __syncthreads();
    for (int off = 1; off < 1024; off <<= 1) {
        int v = (tid >= off) ? lsum[tid - off] : 0;
        __syncthreads();
        lsum[tid] += v;
        __syncthreads();
    }
    int running = lsum[tid] - s;
    for (int j = 0; j < per; ++j) {
        int i = start + j;
        if (i < n) {
            offs[i] = running;
            cur[i]  = running;
            running += cnt[i];
        }
    }
    if (tid == 1023) offs[n] = lsum[1023];
}

// ---------------- fill CSR col lists ----------------
__global__ void fill_k(const int* __restrict__ rows, const int* __restrict__ cols, int E,
                       int* __restrict__ cur, int* __restrict__ col_list) {
    int e = blockIdx.x * blockDim.x + threadIdx.x;
    if (e < E) {
        int r = rows[e];
        int p = atomicAdd(&cur[r], 1);
        col_list[p] = cols[e];
    }
}

// ---------------- expand offs -> row_list (CSR-ordered row ids) ----------------
// wave per row; coalesced sequential writes. blockIdx.y: 0=pos, 1=neg.
__global__ __launch_bounds__(256) void expand_rows_k(
        const int* __restrict__ offs_p, const int* __restrict__ offs_n,
        int* __restrict__ rowl_p, int* __restrict__ rowl_n, int n) {
    int y = blockIdx.y;
    const int* offs = y ? offs_n : offs_p;
    int* rowl = y ? rowl_n : rowl_p;
    int gid  = (blockIdx.x * blockDim.x + threadIdx.x) >> 6;
    int lane = threadIdx.x & 63;
    if (gid >= n) return;
    int beg = offs[gid], end = offs[gid + 1];
    for (int i = beg + lane; i < end; i += 64) rowl[i] = gid;
}

// ---------------- fused pos+neg CSR gather-mean from X (blockIdx.y selects) ----------------
// wave per row, lane = dim; unroll 8 -> 8 independent row loads in flight.
__global__ __launch_bounds__(256) void gatherX_k(
        const float* __restrict__ X,
        const int* __restrict__ offs_p, const int* __restrict__ col_p,
        const int* __restrict__ offs_n, const int* __restrict__ col_n,
        float* __restrict__ a1, float* __restrict__ a2, int n) {
    int y = blockIdx.y;
    const int* offs = y ? offs_n : offs_p;
    const int* cols = y ? col_n : col_p;
    float* o = y ? a2 : a1;
    int gid  = (blockIdx.x * blockDim.x + threadIdx.x) >> 6;
    int lane = threadIdx.x & 63;
    if (gid >= n) return;
    int beg = offs[gid], end = offs[gid + 1];
    float a = 0.f;
    int e = beg;
    for (; e + 7 < end; e += 8) {
        int c0 = cols[e],     c1 = cols[e + 1], c2 = cols[e + 2], c3 = cols[e + 3];
        int c4 = cols[e + 4], c5 = cols[e + 5], c6 = cols[e + 6], c7 = cols[e + 7];
        float v0 = X[(size_t)c0 * DFEAT + lane];
        float v1 = X[(size_t)c1 * DFEAT + lane];
        float v2 = X[(size_t)c2 * DFEAT + lane];
        float v3 = X[(size_t)c3 * DFEAT + lane];
        float v4 = X[(size_t)c4 * DFEAT + lane];
        float v5 = X[(size_t)c5 * DFEAT + lane];
        float v6 = X[(size_t)c6 * DFEAT + lane];
        float v7 = X[(size_t)c7 * DFEAT + lane];
        a += ((v0 + v1) + (v2 + v3)) + ((v4 + v5) + (v6 + v7));
    }
    for (; e + 3 < end; e += 4) {
        int c0 = cols[e], c1 = cols[e + 1], c2 = cols[e + 2], c3 = cols[e + 3];
        a += (X[(size_t)c0 * DFEAT + lane] + X[(size_t)c1 * DFEAT + lane])
           + (X[(size_t)c2 * DFEAT + lane] + X[(size_t)c3 * DFEAT + lane]);
    }
    for (; e < end; ++e) a += X[(size_t)cols[e] * DFEAT + lane];
    int deg = end - beg;
    o[(size_t)gid * DFEAT + lane] = a / (float)(deg > 1 ? deg : 1);
}

// ---------------- fused pos+neg dual gather-mean from hcat[n][128] ----------------
// lane l holds dims (2l, 2l+1); lanes 0-31 = h_pos half -> o1, lanes 32-63 = h_neg half -> o2.
// unroll 8 -> 8 independent 512B row loads in flight per wave.
__global__ __launch_bounds__(256) void dual_gather_k(
        const float* __restrict__ hcat,
        const int* __restrict__ offs_p, const int* __restrict__ col_p,
        const int* __restrict__ offs_n, const int* __restrict__ col_n,
        float* __restrict__ a1, float* __restrict__ a2,
        float* __restrict__ z, int n) {
    int y = blockIdx.y;
    const int* offs = y ? offs_n : offs_p;
    const int* cols = y ? col_n : col_p;
    float* o1 = y ? (z + 64) : a1;  int os1 = y ? 128 : 64;
    float* o2 = y ? z        : a2;  int os2 = y ? 128 : 64;

    int gid  = (blockIdx.x * blockDim.x + threadIdx.x) >> 6;
    int lane = threadIdx.x & 63;
    if (gid >= n) return;
    int beg = offs[gid], end = offs[gid + 1];
    float sx = 0.f, sy = 0.f;
    int e = beg;
    for (; e + 7 < end; e += 8) {
        int c0 = cols[e],     c1 = cols[e + 1], c2 = cols[e + 2], c3 = cols[e + 3];
        int c4 = cols[e + 4], c5 = cols[e + 5], c6 = cols[e + 6], c7 = cols[e + 7];
        float2 v0 = *reinterpret_cast<const float2*>(hcat + (size_t)c0 * 128 + lane * 2);
        float2 v1 = *reinterpret_cast<const float2*>(hcat + (size_t)c1 * 128 + lane * 2);
        float2 v2 = *reinterpret_cast<const float2*>(hcat + (size_t)c2 * 128 + lane * 2);
        float2 v3 = *reinterpret_cast<const float2*>(hcat + (size_t)c3 * 128 + lane * 2);
        float2 v4 = *reinterpret_cast<const float2*>(hcat + (size_t)c4 * 128 + lane * 2);
        float2 v5 = *reinterpret_cast<const float2*>(hcat + (size_t)c5 * 128 + lane * 2);
        float2 v6 = *reinterpret_cast<const float2*>(hcat + (size_t)c6 * 128 + lane * 2);
        float2 v7 = *reinterpret_cast<const float2*>(hcat + (size_t)c7 * 128 + lane * 2);
        sx += ((v0.x + v1.x) + (v2.x + v3.x)) + ((v4.x + v5.x) + (v6.x + v7.x));
        sy += ((v0.y + v1.y) + (v2.y + v3.y)) + ((v4.y + v5.y) + (v6.y + v7.y));
    }
    for (; e + 3 < end; e += 4) {
        int c0 = cols[e], c1 = cols[e + 1], c2 = cols[e + 2], c3 = cols[e + 3];
        float2 v0 = *reinterpret_cast<const float2*>(hcat + (size_t)c0 * 128 + lane * 2);
        float2 v1 = *reinterpret_cast<const float2*>(hcat + (size_t)c1 * 128 + lane * 2);
        float2 v2 = *reinterpret_cast<const float2*>(hcat + (size_t)c2 * 128 + lane * 2);
        float2 v3 = *reinterpret_cast<const float2*>(hcat + (size_t)c3 * 128 + lane * 2);
        sx += (v0.x + v1.x) + (v2.x + v3.x);
        sy += (v0.y + v1.y) + (v2.y + v3.y);
    }
    for (; e < end; ++e) {
        float2 v = *reinterpret_cast<const float2*>(hcat + (size_t)cols[e] * 128 + lane * 2);
        sx += v.x; sy += v.y;
    }
    int deg = end - beg;
    float inv = 1.f / (float)(deg > 1 ? deg : 1);
    sx *= inv; sy *= inv;
    if (lane < 32) {
        o1[(size_t)gid * os1 + lane * 2]     = sx;
        o1[(size_t)gid * os1 + lane * 2 + 1] = sy;
    } else {
        o2[(size_t)gid * os2 + (lane - 32) * 2]     = sx;
        o2[(size_t)gid * os2 + (lane - 32) * 2 + 1] = sy;
    }
}

// ---------------- fused: out = tanh(l2norm(concat @ W + b)) ----------------
template<int K, bool HAS2>
__global__ __launch_bounds__(256) void fused_linear_k(
        const float* __restrict__ p1, int s1,
        const float* __restrict__ p2, int s2,
        const float* __restrict__ p3, int s3,
        const float* __restrict__ W, const float* __restrict__ b,
        float* __restrict__ out, int os) {
    __shared__ float Ws[K * 64];
    __shared__ float bs[64];
    __shared__ float cat[4][K];

    for (int idx = threadIdx.x; idx < K * 64; idx += 256) Ws[idx] = W[idx];
    if (threadIdx.x < 64) bs[threadIdx.x] = b[threadIdx.x];

    int wave = threadIdx.x >> 6;
    int lane = threadIdx.x & 63;
    int row  = blockIdx.x * 4 + wave;      // grid sized exactly: n % 4 == 0

    cat[wave][lane] = p1[(size_t)row * s1 + lane];
    if (HAS2) {
        cat[wave][64 + lane]  = p2[(size_t)row * s2 + lane];
        cat[wave][128 + lane] = p3[(size_t)row * s3 + lane];
    } else {
        cat[wave][64 + lane]  = p3[(size_t)row * s3 + lane];
    }
    __syncthreads();

    float acc = 0.f;
    #pragma unroll
    for (int k = 0; k < K; k += 4) {
        float4 cv = *reinterpret_cast<const float4*>(&cat[wave][k]);  // broadcast
        acc = fmaf(cv.x, Ws[(k + 0) * 64 + lane], acc);
        acc = fmaf(cv.y, Ws[(k + 1) * 64 + lane], acc);
        acc = fmaf(cv.z, Ws[(k + 2) * 64 + lane], acc);
        acc = fmaf(cv.w, Ws[(k + 3) * 64 + lane], acc);
    }
    float v = acc + bs[lane];
    float ss = v * v;
    #pragma unroll
    for (int i = 1; i < 64; i <<= 1) ss += __shfl_xor(ss, i);
    float denom = fmaxf(sqrtf(ss), 1e-12f);
    out[(size_t)row * os + lane] = tanhf(v / denom);
}

// ---------------- normalize z rows -> bf16 table zn[n][128] ----------------
__global__ __launch_bounds__(256) void normalize_k(
        const float* __restrict__ z, u16* __restrict__ zn, int n) {
    int gid  = (blockIdx.x * blockDim.x + threadIdx.x) >> 6;
    int lane = threadIdx.x & 63;
    if (gid >= n) return;
    float v0 = z[(size_t)gid * 128 + lane * 2];
    float v1 = z[(size_t)gid * 128 + lane * 2 + 1];
    float ss = v0 * v0 + v1 * v1;
    #pragma unroll
    for (int o = 1; o < 64; o <<= 1) ss += __shfl_xor(ss, o);
    float inv = 1.f / fmaxf(sqrtf(ss), 1e-8f);
    __hip_bfloat16 b0 = __float2bfloat16(v0 * inv);
    __hip_bfloat16 b1 = __float2bfloat16(v1 * inv);
    u16 s0 = *reinterpret_cast<u16*>(&b0);
    u16 s1 = *reinterpret_cast<u16*>(&b1);
    u32 packed = (u32)s0 | ((u32)s1 << 16);
    *reinterpret_cast<u32*>(zn + (size_t)gid * 128 + lane * 2) = packed;
}

// ---------------- logits + log_softmax + argmax ----------------
__global__ __launch_bounds__(256) void logits_k(
        const float* __restrict__ z, const float* __restrict__ Wr,
        const float* __restrict__ br, const int* __restrict__ comm,
        float* __restrict__ clar_f, int* __restrict__ clar_i,
        float* __restrict__ lp_sum, int n) {
    __shared__ float Wl[128 * 3];
    for (int idx = threadIdx.x; idx < 384; idx += blockDim.x) Wl[idx] = Wr[idx];
    __syncthreads();
    int i = blockIdx.x * blockDim.x + threadIdx.x;
    float lp = 0.f;
    if (i < n) {
        float l0 = br[0], l1 = br[1], l2 = br[2];
        const float* zr = z + (size_t)i * 128;
        #pragma unroll 4
        for (int k = 0; k < 128; k += 4) {
            float4 v = *reinterpret_cast<const float4*>(zr + k);
            float zz[4] = {v.x, v.y, v.z, v.w};
            #pragma unroll
            for (int j = 0; j < 4; ++j) {
                float zv = zz[j];
                int kk = k + j;
                l0 = fmaf(zv, Wl[3 * kk + 0], l0);
                l1 = fmaf(zv, Wl[3 * kk + 1], l1);
                l2 = fmaf(zv, Wl[3 * kk + 2], l2);
            }
        }
        int idx = 0; float mv = l0;
        if (l1 > mv) { mv = l1; idx = 1; }
        if (l2 > mv) { mv = l2; idx = 2; }
        clar_i[i] = idx;
        clar_f[i] = (float)idx;
        float lse = mv + logf(expf(l0 - mv) + expf(l1 - mv) + expf(l2 - mv));
        int c = comm[i];
        lp = (c == 0 ? l0 : (c == 1 ? l1 : l2)) - lse;
    }
    #pragma unroll
    for (int o = 1; o < 64; o <<= 1) lp += __shfl_xor(lp, o);
    __shared__ float wsum[4];
    if ((threadIdx.x & 63) == 0) wsum[threadIdx.x >> 6] = lp;
    __syncthreads();
    if (threadIdx.x == 0) atomicAdd(lp_sum, wsum[0] + wsum[1] + wsum[2] + wsum[3]);
}

// ---------------- edge-parallel cosine-sim losses over CSR-ordered lists ----------------
// 16 lanes per edge, no loop: each wave = 4 edges, 8 independent 256B row loads
// in flight, then retires (MLP via wave turnover). CSR order -> consecutive
// edges share the a-row (L1/L2 hit). clar pre-check skips unselected rows.
// blockIdx.y = mode. MODE 0: sum max(cos,0) where clarify differs;
//                    MODE 1: sum -min(cos,0) where clarify equal.
__global__ __launch_bounds__(256) void sim_edge_k(
        const u16* __restrict__ zn, const int* __restrict__ clar,
        const int* __restrict__ rowl_p, const int* __restrict__ col_p,
        const int* __restrict__ rowl_n, const int* __restrict__ col_n,
        float* __restrict__ scal, int E) {
    int mode = blockIdx.y;
    const int* rowl = mode ? rowl_n : rowl_p;
    const int* cols = mode ? col_n : col_p;
    int t   = blockIdx.x * blockDim.x + threadIdx.x;
    int e   = t >> 4;
    int sub = t & 15;
    float total = 0.f;
    if (e < E) {
        int a = rowl[e], b = cols[e];
        int ca = clar[a], cb = clar[b];
        bool sel = mode ? (cb == ca) : (cb != ca);
        if (sel) {
            uint4 ua = *reinterpret_cast<const uint4*>(zn + (size_t)a * 128 + sub * 8);
            uint4 ub = *reinterpret_cast<const uint4*>(zn + (size_t)b * 128 + sub * 8);
            float d;
            d = bflo(ua.x) * bflo(ub.x);
            d = fmaf(bfhi(ua.x), bfhi(ub.x), d);
            d = fmaf(bflo(ua.y), bflo(ub.y), d);
            d = fmaf(bfhi(ua.y), bfhi(ub.y), d);
            d = fmaf(bflo(ua.z), bflo(ub.z), d);
            d = fmaf(bfhi(ua.z), bfhi(ub.z), d);
            d = fmaf(bflo(ua.w), bflo(ub.w), d);
            d = fmaf(bfhi(ua.w), bfhi(ub.w), d);
            d += __shfl_xor(d, 1);
            d += __shfl_xor(d, 2);
            d += __shfl_xor(d, 4);
            d += __shfl_xor(d, 8);
            if (sub == 0) total = mode ? -fminf(d, 0.f) : fmaxf(d, 0.f);
        }
    }
    // only sub==0 lanes hold a value; finish the 64-lane reduce
    total += __shfl_xor(total, 16);
    total += __shfl_xor(total, 32);
    __shared__ float wsum[4];
    if ((threadIdx.x & 63) == 0) wsum[threadIdx.x >> 6] = total;
    __syncthreads();
    if (threadIdx.x == 0) atomicAdd(&scal[1 + mode], wsum[0] + wsum[1] + wsum[2] + wsum[3]);
}

__global__ void finalize_k(const float* __restrict__ scal, float* __restrict__ out,
                           int n, int E) {
    if (threadIdx.x == 0 && blockIdx.x == 0) {
        float reg_loss = -scal[0] / (float)n;
        float sim1 = scal[1] / (float)E;
        float sim2 = scal[2] / (float)E;
        out[0] = 0.8f * reg_loss + 0.2f * (sim1 + sim2);
    }
}

extern "C" void kernel_launch(void* const* d_in, const int* in_sizes, int n_in,
                              void* d_out, int out_size, void* d_ws, size_t ws_size,
                              hipStream_t stream) {
    const float* X   = (const float*)d_in[0];
    const float* pbW = (const float*)d_in[1];
    const float* pbB = (const float*)d_in[2];
    const float* nbW = (const float*)d_in[3];
    const float* nbB = (const float*)d_in[4];
    const float* pdW = (const float*)d_in[5];
    const float* pdB = (const float*)d_in[6];
    const float* ndW = (const float*)d_in[7];
    const float* ndB = (const float*)d_in[8];
    const float* rW  = (const float*)d_in[9];
    const float* rB  = (const float*)d_in[10];
    const int* pe    = (const int*)d_in[11];
    const int* ne    = (const int*)d_in[12];
    const int* comm  = (const int*)d_in[13];

    const int E = in_sizes[11] / 2;          // 800000
    const int n = in_sizes[0] / DFEAT;       // 50000

    float* out    = (float*)d_out;
    float* z      = out + 1;                             // [n,128]
    float* clar_f = out + 1 + (size_t)n * 128;           // [n]

    // workspace layout
    char*  w   = (char*)d_ws;
    size_t big = (size_t)n * DFEAT * sizeof(float);      // 12.8 MB
    float* a1    = (float*)(w);                          // [n,64]; later zn (bf16 [n,128])
    float* a2    = (float*)(w + big);                    // [n,64]; later rowl_p|rowl_n (2E ints = 6.4MB)
    float* hcat  = (float*)(w + 2 * big);                // [n,128] = h_pos | h_neg
    u16*   zn    = (u16*)a1;                             // n*128*2B == big exactly
    int*   rowl_p = (int*)a2;                            // E ints (after deep linears)
    int*   rowl_n = rowl_p + E;                          // E ints
    char*  sm    = w + 4 * big;
    int* col_p  = (int*)sm;  sm += (size_t)E * 4;
    int* col_n  = (int*)sm;  sm += (size_t)E * 4;
    int* offs   = (int*)sm;  sm += 2 * (size_t)(n + 1) * 4;  // offs_p | offs_n
    int* cur    = (int*)sm;  sm += 2 * (size_t)n * 4;        // cur_p | cur_n
    int* cnt    = (int*)sm;  sm += 2 * (size_t)n * 4;        // cnt_p | cnt_n
    int* clar_i = (int*)sm;  sm += (size_t)n * 4;
    float* scal = (float*)sm; sm += 64;   // [0]=lp_sum [1]=sim1 [2]=sim2

    int* offs_p = offs;
    int* offs_n = offs + (n + 1);
    int* cur_p  = cur;
    int* cur_n  = cur + n;
    int* cnt_p  = cnt;
    int* cnt_n  = cnt + n;

    const int* rp = pe, *cp = pe + E;
    const int* rn = ne, *cn = ne + E;

    const int egrid = (E + 255) / 256;
    const int ngrid = (n + 255) / 256;
    const int fgrid = n / 4;                 // n % 4 == 0 (12500)
    const int sgrid = (E * 16 + 255) / 256;  // 50000

    // zero only small accumulators (ws is poisoned each call)
    hipMemsetAsync(cnt, 0, 2 * (size_t)n * 4, stream);
    hipMemsetAsync(scal, 0, 64, stream);

    // ---- CSR build (pos & neg), reused by all aggregations + sims ----
    count_edges_k<<<egrid, 256, 0, stream>>>(rp, E, cnt_p);
    count_edges_k<<<egrid, 256, 0, stream>>>(rn, E, cnt_n);
    scan_k<<<2, 1024, 0, stream>>>(cnt, n, offs, cur);
    fill_k<<<egrid, 256, 0, stream>>>(rp, cp, E, cur_p, col_p);
    fill_k<<<egrid, 256, 0, stream>>>(rn, cn, E, cur_n, col_n);

    // ---- layer 0 (base): both CSR gathers in one dispatch ----
    gatherX_k<<<dim3(fgrid, 2), 256, 0, stream>>>(X, offs_p, col_p, offs_n, col_n, a1, a2, n);
    // h_pos -> hcat[:, 0:64], h_neg -> hcat[:, 64:128]
    fused_linear_k<128, false><<<fgrid, 256, 0, stream>>>(a1, 64, nullptr, 0, X, 64, pbW, pbB, hcat, 128);
    fused_linear_k<128, false><<<fgrid, 256, 0, stream>>>(a2, 64, nullptr, 0, X, 64, nbW, nbB, hcat + 64, 128);

    // ---- deep-layer aggregations: both CSRs in one dispatch ----
    // y=0 (pos-CSR): mean h_pos -> a1, mean h_neg -> a2
    // y=1 (neg-CSR): mean h_pos -> z[:,64:], mean h_neg -> z[:,:64]
    dual_gather_k<<<dim3(fgrid, 2), 256, 0, stream>>>(hcat, offs_p, col_p, offs_n, col_n, a1, a2, z, n);

    // ---- deep linears (p2 in-place per-row with out: safe, per-row reads precede write) ----
    fused_linear_k<192, true><<<fgrid, 256, 0, stream>>>(a1, 64, z, 128, hcat, 128, pdW, pdB, z, 128);
    fused_linear_k<192, true><<<fgrid, 256, 0, stream>>>(a2, 64, z + 64, 128, hcat + 64, 128, ndW, ndB, z + 64, 128);

    // ---- a1/a2 free now: build zn (bf16 normalized z) and CSR row lists ----
    normalize_k<<<fgrid, 256, 0, stream>>>(z, zn, n);
    expand_rows_k<<<dim3(fgrid, 2), 256, 0, stream>>>(offs_p, offs_n, rowl_p, rowl_n, n);

    // ---- losses ----
    logits_k<<<ngrid, 256, 0, stream>>>(z, rW, rB, comm, clar_f, clar_i, &scal[0], n);
    sim_edge_k<<<dim3(sgrid, 2), 256, 0, stream>>>(zn, clar_i, rowl_p, col_p, rowl_n, col_n, scal, E);
    finalize_k<<<1, 64, 0, stream>>>(scal, out, n, E);
}

// Round 10
// 928.534 us; speedup vs baseline: 2.3786x; 2.3786x over previous
//
#include <hip/hip_runtime.h>
#include <hip/hip_bf16.h>
#include <math.h>

// Problem constants (from reference): N=50000, D=64, E=800000, H=64
#define DFEAT 64

typedef unsigned int u32;
typedef unsigned short u16;

// bf16(hi 16 bits of f32) -> f32, exact
__device__ inline float bflo(u32 u) { return __uint_as_float(u << 16); }
__device__ inline float bfhi(u32 u) { return __uint_as_float(u & 0xffff0000u); }

// ---------------- count in-degree (int atomics, cheap) ----------------
__global__ void count_edges_k(const int* __restrict__ rows, int E, int* __restrict__ cnt) {
    int e = blockIdx.x * blockDim.x + threadIdx.x;
    if (e < E) atomicAdd(&cnt[rows[e]], 1);
}

// ---------------- exclusive scan of counts -> CSR offsets + cursor ----------------
__global__ __launch_bounds__(1024) void scan_k(const int* __restrict__ cnt_all, int n,
                                               int* __restrict__ offs_all, int* __restrict__ cur_all) {
    const int* cnt = cnt_all + (size_t)blockIdx.x * n;
    int* offs = offs_all + (size_t)blockIdx.x * (n + 1);
    int* cur  = cur_all  + (size_t)blockIdx.x * n;

    __shared__ int lsum[1024];
    int tid = threadIdx.x;
    int per = (n + 1023) / 1024;
    int start = tid * per;
    int s = 0;
    for (int j = 0; j < per; ++j) {
        int i = start + j;
        if (i < n) s += cnt[i];
    }
    lsum[tid] = s;
    __syncthreads();
    for (int off = 1; off < 1024; off <<= 1) {
        int v = (tid >= off) ? lsum[tid - off] : 0;
        __syncthreads();
        lsum[tid] += v;
        __syncthreads();
    }
    int running = lsum[tid] - s;
    for (int j = 0; j < per; ++j) {
        int i = start + j;
        if (i < n) {
            offs[i] = running;
            cur[i]  = running;
            running += cnt[i];
        }
    }
    if (tid == 1023) offs[n] = lsum[1023];
}

// ---------------- fill CSR col lists ----------------
__global__ void fill_k(const int* __restrict__ rows, const int* __restrict__ cols, int E,
                       int* __restrict__ cur, int* __restrict__ col_list) {
    int e = blockIdx.x * blockDim.x + threadIdx.x;
    if (e < E) {
        int r = rows[e];
        int p = atomicAdd(&cur[r], 1);
        col_list[p] = cols[e];
    }
}

// ---------------- fused pos+neg CSR gather-mean from X (blockIdx.y selects) ----------------
// wave per row, lane = dim; unroll 8 -> 8 independent row loads in flight.
__global__ __launch_bounds__(256) void gatherX_k(
        const float* __restrict__ X,
        const int* __restrict__ offs_p, const int* __restrict__ col_p,
        const int* __restrict__ offs_n, const int* __restrict__ col_n,
        float* __restrict__ a1, float* __restrict__ a2, int n) {
    int y = blockIdx.y;
    const int* offs = y ? offs_n : offs_p;
    const int* cols = y ? col_n : col_p;
    float* o = y ? a2 : a1;
    int gid  = (blockIdx.x * blockDim.x + threadIdx.x) >> 6;
    int lane = threadIdx.x & 63;
    if (gid >= n) return;
    int beg = offs[gid], end = offs[gid + 1];
    float a = 0.f;
    int e = beg;
    for (; e + 7 < end; e += 8) {
        int c0 = cols[e],     c1 = cols[e + 1], c2 = cols[e + 2], c3 = cols[e + 3];
        int c4 = cols[e + 4], c5 = cols[e + 5], c6 = cols[e + 6], c7 = cols[e + 7];
        float v0 = X[(size_t)c0 * DFEAT + lane];
        float v1 = X[(size_t)c1 * DFEAT + lane];
        float v2 = X[(size_t)c2 * DFEAT + lane];
        float v3 = X[(size_t)c3 * DFEAT + lane];
        float v4 = X[(size_t)c4 * DFEAT + lane];
        float v5 = X[(size_t)c5 * DFEAT + lane];
        float v6 = X[(size_t)c6 * DFEAT + lane];
        float v7 = X[(size_t)c7 * DFEAT + lane];
        a += ((v0 + v1) + (v2 + v3)) + ((v4 + v5) + (v6 + v7));
    }
    for (; e + 3 < end; e += 4) {
        int c0 = cols[e], c1 = cols[e + 1], c2 = cols[e + 2], c3 = cols[e + 3];
        a += (X[(size_t)c0 * DFEAT + lane] + X[(size_t)c1 * DFEAT + lane])
           + (X[(size_t)c2 * DFEAT + lane] + X[(size_t)c3 * DFEAT + lane]);
    }
    for (; e < end; ++e) a += X[(size_t)cols[e] * DFEAT + lane];
    int deg = end - beg;
    o[(size_t)gid * DFEAT + lane] = a / (float)(deg > 1 ? deg : 1);
}

// ---------------- fused pos+neg dual gather-mean from hcat[n][128] ----------------
// lane l holds dims (2l, 2l+1); lanes 0-31 = h_pos half -> o1, lanes 32-63 = h_neg half -> o2.
// unroll 8 -> 8 independent 512B row loads in flight per wave.
__global__ __launch_bounds__(256) void dual_gather_k(
        const float* __restrict__ hcat,
        const int* __restrict__ offs_p, const int* __restrict__ col_p,
        const int* __restrict__ offs_n, const int* __restrict__ col_n,
        float* __restrict__ a1, float* __restrict__ a2,
        float* __restrict__ z, int n) {
    int y = blockIdx.y;
    const int* offs = y ? offs_n : offs_p;
    const int* cols = y ? col_n : col_p;
    float* o1 = y ? (z + 64) : a1;  int os1 = y ? 128 : 64;
    float* o2 = y ? z        : a2;  int os2 = y ? 128 : 64;

    int gid  = (blockIdx.x * blockDim.x + threadIdx.x) >> 6;
    int lane = threadIdx.x & 63;
    if (gid >= n) return;
    int beg = offs[gid], end = offs[gid + 1];
    float sx = 0.f, sy = 0.f;
    int e = beg;
    for (; e + 7 < end; e += 8) {
        int c0 = cols[e],     c1 = cols[e + 1], c2 = cols[e + 2], c3 = cols[e + 3];
        int c4 = cols[e + 4], c5 = cols[e + 5], c6 = cols[e + 6], c7 = cols[e + 7];
        float2 v0 = *reinterpret_cast<const float2*>(hcat + (size_t)c0 * 128 + lane * 2);
        float2 v1 = *reinterpret_cast<const float2*>(hcat + (size_t)c1 * 128 + lane * 2);
        float2 v2 = *reinterpret_cast<const float2*>(hcat + (size_t)c2 * 128 + lane * 2);
        float2 v3 = *reinterpret_cast<const float2*>(hcat + (size_t)c3 * 128 + lane * 2);
        float2 v4 = *reinterpret_cast<const float2*>(hcat + (size_t)c4 * 128 + lane * 2);
        float2 v5 = *reinterpret_cast<const float2*>(hcat + (size_t)c5 * 128 + lane * 2);
        float2 v6 = *reinterpret_cast<const float2*>(hcat + (size_t)c6 * 128 + lane * 2);
        float2 v7 = *reinterpret_cast<const float2*>(hcat + (size_t)c7 * 128 + lane * 2);
        sx += ((v0.x + v1.x) + (v2.x + v3.x)) + ((v4.x + v5.x) + (v6.x + v7.x));
        sy += ((v0.y + v1.y) + (v2.y + v3.y)) + ((v4.y + v5.y) + (v6.y + v7.y));
    }
    for (; e + 3 < end; e += 4) {
        int c0 = cols[e], c1 = cols[e + 1], c2 = cols[e + 2], c3 = cols[e + 3];
        float2 v0 = *reinterpret_cast<const float2*>(hcat + (size_t)c0 * 128 + lane * 2);
        float2 v1 = *reinterpret_cast<const float2*>(hcat + (size_t)c1 * 128 + lane * 2);
        float2 v2 = *reinterpret_cast<const float2*>(hcat + (size_t)c2 * 128 + lane * 2);
        float2 v3 = *reinterpret_cast<const float2*>(hcat + (size_t)c3 * 128 + lane * 2);
        sx += (v0.x + v1.x) + (v2.x + v3.x);
        sy += (v0.y + v1.y) + (v2.y + v3.y);
    }
    for (; e < end; ++e) {
        float2 v = *reinterpret_cast<const float2*>(hcat + (size_t)cols[e] * 128 + lane * 2);
        sx += v.x; sy += v.y;
    }
    int deg = end - beg;
    float inv = 1.f / (float)(deg > 1 ? deg : 1);
    sx *= inv; sy *= inv;
    if (lane < 32) {
        o1[(size_t)gid * os1 + lane * 2]     = sx;
        o1[(size_t)gid * os1 + lane * 2 + 1] = sy;
    } else {
        o2[(size_t)gid * os2 + (lane - 32) * 2]     = sx;
        o2[(size_t)gid * os2 + (lane - 32) * 2 + 1] = sy;
    }
}

// ---------------- fused: out = tanh(l2norm(concat @ W + b)) ----------------
template<int K, bool HAS2>
__global__ __launch_bounds__(256) void fused_linear_k(
        const float* __restrict__ p1, int s1,
        const float* __restrict__ p2, int s2,
        const float* __restrict__ p3, int s3,
        const float* __restrict__ W, const float* __restrict__ b,
        float* __restrict__ out, int os) {
    __shared__ float Ws[K * 64];
    __shared__ float bs[64];
    __shared__ float cat[4][K];

    for (int idx = threadIdx.x; idx < K * 64; idx += 256) Ws[idx] = W[idx];
    if (threadIdx.x < 64) bs[threadIdx.x] = b[threadIdx.x];

    int wave = threadIdx.x >> 6;
    int lane = threadIdx.x & 63;
    int row  = blockIdx.x * 4 + wave;      // grid sized exactly: n % 4 == 0

    cat[wave][lane] = p1[(size_t)row * s1 + lane];
    if (HAS2) {
        cat[wave][64 + lane]  = p2[(size_t)row * s2 + lane];
        cat[wave][128 + lane] = p3[(size_t)row * s3 + lane];
    } else {
        cat[wave][64 + lane]  = p3[(size_t)row * s3 + lane];
    }
    __syncthreads();

    float acc = 0.f;
    #pragma unroll
    for (int k = 0; k < K; k += 4) {
        float4 cv = *reinterpret_cast<const float4*>(&cat[wave][k]);  // broadcast
        acc = fmaf(cv.x, Ws[(k + 0) * 64 + lane], acc);
        acc = fmaf(cv.y, Ws[(k + 1) * 64 + lane], acc);
        acc = fmaf(cv.z, Ws[(k + 2) * 64 + lane], acc);
        acc = fmaf(cv.w, Ws[(k + 3) * 64 + lane], acc);
    }
    float v = acc + bs[lane];
    float ss = v * v;
    #pragma unroll
    for (int i = 1; i < 64; i <<= 1) ss += __shfl_xor(ss, i);
    float denom = fmaxf(sqrtf(ss), 1e-12f);
    out[(size_t)row * os + lane] = tanhf(v / denom);
}

// ---------------- normalize z rows -> bf16 table zn[n][128] ----------------
__global__ __launch_bounds__(256) void normalize_k(
        const float* __restrict__ z, u16* __restrict__ zn, int n) {
    int gid  = (blockIdx.x * blockDim.x + threadIdx.x) >> 6;
    int lane = threadIdx.x & 63;
    if (gid >= n) return;
    float v0 = z[(size_t)gid * 128 + lane * 2];
    float v1 = z[(size_t)gid * 128 + lane * 2 + 1];
    float ss = v0 * v0 + v1 * v1;
    #pragma unroll
    for (int o = 1; o < 64; o <<= 1) ss += __shfl_xor(ss, o);
    float inv = 1.f / fmaxf(sqrtf(ss), 1e-8f);
    __hip_bfloat16 b0 = __float2bfloat16(v0 * inv);
    __hip_bfloat16 b1 = __float2bfloat16(v1 * inv);
    u16 s0 = *reinterpret_cast<u16*>(&b0);
    u16 s1 = *reinterpret_cast<u16*>(&b1);
    u32 packed = (u32)s0 | ((u32)s1 << 16);
    *reinterpret_cast<u32*>(zn + (size_t)gid * 128 + lane * 2) = packed;
}

// ---------------- logits + log_softmax + argmax ----------------
__global__ __launch_bounds__(256) void logits_k(
        const float* __restrict__ z, const float* __restrict__ Wr,
        const float* __restrict__ br, const int* __restrict__ comm,
        float* __restrict__ clar_f, int* __restrict__ clar_i,
        float* __restrict__ lp_sum, int n) {
    __shared__ float Wl[128 * 3];
    for (int idx = threadIdx.x; idx < 384; idx += blockDim.x) Wl[idx] = Wr[idx];
    __syncthreads();
    int i = blockIdx.x * blockDim.x + threadIdx.x;
    float lp = 0.f;
    if (i < n) {
        float l0 = br[0], l1 = br[1], l2 = br[2];
        const float* zr = z + (size_t)i * 128;
        #pragma unroll 4
        for (int k = 0; k < 128; k += 4) {
            float4 v = *reinterpret_cast<const float4*>(zr + k);
            float zz[4] = {v.x, v.y, v.z, v.w};
            #pragma unroll
            for (int j = 0; j < 4; ++j) {
                float zv = zz[j];
                int kk = k + j;
                l0 = fmaf(zv, Wl[3 * kk + 0], l0);
                l1 = fmaf(zv, Wl[3 * kk + 1], l1);
                l2 = fmaf(zv, Wl[3 * kk + 2], l2);
            }
        }
        int idx = 0; float mv = l0;
        if (l1 > mv) { mv = l1; idx = 1; }
        if (l2 > mv) { mv = l2; idx = 2; }
        clar_i[i] = idx;
        clar_f[i] = (float)idx;
        float lse = mv + logf(expf(l0 - mv) + expf(l1 - mv) + expf(l2 - mv));
        int c = comm[i];
        lp = (c == 0 ? l0 : (c == 1 ? l1 : l2)) - lse;
    }
    #pragma unroll
    for (int o = 1; o < 64; o <<= 1) lp += __shfl_xor(lp, o);
    __shared__ float wsum[4];
    if ((threadIdx.x & 63) == 0) wsum[threadIdx.x >> 6] = lp;
    __syncthreads();
    if (threadIdx.x == 0) atomicAdd(lp_sum, wsum[0] + wsum[1] + wsum[2] + wsum[3]);
}

// ---------------- CSR-row-grouped cosine-sim losses, GRID-STRIDED ----------------
// Fixed grid (1024 blocks x 2 modes) -> exactly 2048 atomics total (was 100k:
// the per-block atomicAdd to ONE address serializes at ~14ns; block count must
// stay small). One wave per row per iteration: zn[a] in regs, clar pre-check
// skips the 256B row load for unselected edges, 4 edges in flight x unroll 2.
__global__ __launch_bounds__(256) void sim_rows_k(
        const u16* __restrict__ zn, const int* __restrict__ clar,
        const int* __restrict__ offs_p, const int* __restrict__ col_p,
        const int* __restrict__ offs_n, const int* __restrict__ col_n,
        float* __restrict__ scal, int n) {
    int mode = blockIdx.y;
    const int* offs = mode ? offs_n : offs_p;
    const int* cols = mode ? col_n : col_p;
    int lane = threadIdx.x & 63;
    int sub  = lane & 15;
    int q    = lane >> 4;
    int wid    = blockIdx.x * 4 + (threadIdx.x >> 6);
    int nwaves = gridDim.x * 4;
    float total = 0.f;
    for (int gid = wid; gid < n; gid += nwaves) {
        uint4 ua = *reinterpret_cast<const uint4*>(zn + (size_t)gid * 128 + sub * 8);
        float a0 = bflo(ua.x), a1 = bfhi(ua.x), a2 = bflo(ua.y), a3 = bfhi(ua.y);
        float a4 = bflo(ua.z), a5 = bfhi(ua.z), a6 = bflo(ua.w), a7 = bfhi(ua.w);
        int ca = clar[gid];
        int beg = offs[gid], end = offs[gid + 1];
        #pragma unroll 2
        for (int e = beg + q; e < end; e += 4) {
            int b = cols[e];
            int cb = clar[b];                 // L2-hot 200KB table, checked pre-load
            bool sel = mode ? (cb == ca) : (cb != ca);
            if (sel) {
                uint4 ub = *reinterpret_cast<const uint4*>(zn + (size_t)b * 128 + sub * 8);
                float d;
                d = a0 * bflo(ub.x);
                d = fmaf(a1, bfhi(ub.x), d);
                d = fmaf(a2, bflo(ub.y), d);
                d = fmaf(a3, bfhi(ub.y), d);
                d = fmaf(a4, bflo(ub.z), d);
                d = fmaf(a5, bfhi(ub.z), d);
                d = fmaf(a6, bflo(ub.w), d);
                d = fmaf(a7, bfhi(ub.w), d);
                d += __shfl_xor(d, 1);
                d += __shfl_xor(d, 2);
                d += __shfl_xor(d, 4);
                d += __shfl_xor(d, 8);
                if (sub == 0) total += mode ? -fminf(d, 0.f) : fmaxf(d, 0.f);
            }
        }
    }
    // non-sub0 lanes hold 0; full 64-lane reduce then one atomic per block
    #pragma unroll
    for (int o = 1; o < 64; o <<= 1) total += __shfl_xor(total, o);
    __shared__ float wsum[4];
    if ((threadIdx.x & 63) == 0) wsum[threadIdx.x >> 6] = total;
    __syncthreads();
    if (threadIdx.x == 0) atomicAdd(&scal[1 + mode], wsum[0] + wsum[1] + wsum[2] + wsum[3]);
}

__global__ void finalize_k(const float* __restrict__ scal, float* __restrict__ out,
                           int n, int E) {
    if (threadIdx.x == 0 && blockIdx.x == 0) {
        float reg_loss = -scal[0] / (float)n;
        float sim1 = scal[1] / (float)E;
        float sim2 = scal[2] / (float)E;
        out[0] = 0.8f * reg_loss + 0.2f * (sim1 + sim2);
    }
}

extern "C" void kernel_launch(void* const* d_in, const int* in_sizes, int n_in,
                              void* d_out, int out_size, void* d_ws, size_t ws_size,
                              hipStream_t stream) {
    const float* X   = (const float*)d_in[0];
    const float* pbW = (const float*)d_in[1];
    const float* pbB = (const float*)d_in[2];
    const float* nbW = (const float*)d_in[3];
    const float* nbB = (const float*)d_in[4];
    const float* pdW = (const float*)d_in[5];
    const float* pdB = (const float*)d_in[6];
    const float* ndW = (const float*)d_in[7];
    const float* ndB = (const float*)d_in[8];
    const float* rW  = (const float*)d_in[9];
    const float* rB  = (const float*)d_in[10];
    const int* pe    = (const int*)d_in[11];
    const int* ne    = (const int*)d_in[12];
    const int* comm  = (const int*)d_in[13];

    const int E = in_sizes[11] / 2;          // 800000
    const int n = in_sizes[0] / DFEAT;       // 50000

    float* out    = (float*)d_out;
    float* z      = out + 1;                             // [n,128]
    float* clar_f = out + 1 + (size_t)n * 128;           // [n]

    // workspace layout
    char*  w   = (char*)d_ws;
    size_t big = (size_t)n * DFEAT * sizeof(float);      // 12.8 MB
    float* a1    = (float*)(w);                          // [n,64]; later zn (bf16 [n,128])
    float* a2    = (float*)(w + big);                    // [n,64]
    float* hcat  = (float*)(w + 2 * big);                // [n,128] = h_pos | h_neg
    u16*   zn    = (u16*)a1;                             // n*128*2B == big exactly
    char*  sm    = w + 4 * big;
    int* col_p  = (int*)sm;  sm += (size_t)E * 4;
    int* col_n  = (int*)sm;  sm += (size_t)E * 4;
    int* offs   = (int*)sm;  sm += 2 * (size_t)(n + 1) * 4;  // offs_p | offs_n
    int* cur    = (int*)sm;  sm += 2 * (size_t)n * 4;        // cur_p | cur_n
    int* cnt    = (int*)sm;  sm += 2 * (size_t)n * 4;        // cnt_p | cnt_n
    int* clar_i = (int*)sm;  sm += (size_t)n * 4;
    float* scal = (float*)sm; sm += 64;   // [0]=lp_sum [1]=sim1 [2]=sim2

    int* offs_p = offs;
    int* offs_n = offs + (n + 1);
    int* cur_p  = cur;
    int* cur_n  = cur + n;
    int* cnt_p  = cnt;
    int* cnt_n  = cnt + n;

    const int* rp = pe, *cp = pe + E;
    const int* rn = ne, *cn = ne + E;

    const int egrid = (E + 255) / 256;
    const int ngrid = (n + 255) / 256;
    const int fgrid = n / 4;                 // n % 4 == 0 (12500)

    // zero only small accumulators (ws is poisoned each call)
    hipMemsetAsync(cnt, 0, 2 * (size_t)n * 4, stream);
    hipMemsetAsync(scal, 0, 64, stream);

    // ---- CSR build (pos & neg), reused by all aggregations + sims ----
    count_edges_k<<<egrid, 256, 0, stream>>>(rp, E, cnt_p);
    count_edges_k<<<egrid, 256, 0, stream>>>(rn, E, cnt_n);
    scan_k<<<2, 1024, 0, stream>>>(cnt, n, offs, cur);
    fill_k<<<egrid, 256, 0, stream>>>(rp, cp, E, cur_p, col_p);
    fill_k<<<egrid, 256, 0, stream>>>(rn, cn, E, cur_n, col_n);

    // ---- layer 0 (base): both CSR gathers in one dispatch ----
    gatherX_k<<<dim3(fgrid, 2), 256, 0, stream>>>(X, offs_p, col_p, offs_n, col_n, a1, a2, n);
    // h_pos -> hcat[:, 0:64], h_neg -> hcat[:, 64:128]
    fused_linear_k<128, false><<<fgrid, 256, 0, stream>>>(a1, 64, nullptr, 0, X, 64, pbW, pbB, hcat, 128);
    fused_linear_k<128, false><<<fgrid, 256, 0, stream>>>(a2, 64, nullptr, 0, X, 64, nbW, nbB, hcat + 64, 128);

    // ---- deep-layer aggregations: both CSRs in one dispatch ----
    // y=0 (pos-CSR): mean h_pos -> a1, mean h_neg -> a2
    // y=1 (neg-CSR): mean h_pos -> z[:,64:], mean h_neg -> z[:,:64]
    dual_gather_k<<<dim3(fgrid, 2), 256, 0, stream>>>(hcat, offs_p, col_p, offs_n, col_n, a1, a2, z, n);

    // ---- deep linears (p2 in-place per-row with out: safe, per-row reads precede write) ----
    fused_linear_k<192, true><<<fgrid, 256, 0, stream>>>(a1, 64, z, 128, hcat, 128, pdW, pdB, z, 128);
    fused_linear_k<192, true><<<fgrid, 256, 0, stream>>>(a2, 64, z + 64, 128, hcat + 64, 128, ndW, ndB, z + 64, 128);

    // ---- normalized bf16 z table (overwrites a1 — free now) ----
    normalize_k<<<fgrid, 256, 0, stream>>>(z, zn, n);

    // ---- losses ----
    logits_k<<<ngrid, 256, 0, stream>>>(z, rW, rB, comm, clar_f, clar_i, &scal[0], n);
    sim_rows_k<<<dim3(1024, 2), 256, 0, stream>>>(zn, clar_i, offs_p, col_p, offs_n, col_n, scal, n);
    finalize_k<<<1, 64, 0, stream>>>(scal, out, n, E);
}

// Round 16
// 840.490 us; speedup vs baseline: 2.6278x; 1.1048x over previous
//
#include <hip/hip_runtime.h>
#include <hip/hip_bf16.h>
#include <math.h>

// Problem constants (from reference): N=50000, D=64, E=800000, H=64
#define DFEAT 64

typedef unsigned int u32;
typedef unsigned short u16;

// bf16(hi 16 bits of f32) -> f32, exact
__device__ inline float bflo(u32 u) { return __uint_as_float(u << 16); }
__device__ inline float bfhi(u32 u) { return __uint_as_float(u & 0xffff0000u); }

// ---------------- count in-degree, pos+neg fused (blockIdx.y) ----------------
__global__ void count_edges_k(const int* __restrict__ rows_p, const int* __restrict__ rows_n,
                              int E, int* __restrict__ cnt_p, int* __restrict__ cnt_n) {
    int y = blockIdx.y;
    const int* rows = y ? rows_n : rows_p;
    int* cnt = y ? cnt_n : cnt_p;
    int e = blockIdx.x * blockDim.x + threadIdx.x;
    if (e < E) atomicAdd(&cnt[rows[e]], 1);
}

// ---------------- multi-block scan, phase A: per-block sums ----------------
// grid (nb, 2) x 1024; one element per thread, coalesced.
__global__ __launch_bounds__(1024) void scan_partial_k(
        const int* __restrict__ cnt_all, int n, int* __restrict__ bsum, int nb) {
    int y = blockIdx.y;
    const int* cnt = cnt_all + (size_t)y * n;
    int i = blockIdx.x * 1024 + threadIdx.x;
    int v = (i < n) ? cnt[i] : 0;
    #pragma unroll
    for (int o = 1; o < 64; o <<= 1) v += __shfl_xor(v, o);
    __shared__ int sdata[16];
    if ((threadIdx.x & 63) == 0) sdata[threadIdx.x >> 6] = v;
    __syncthreads();
    if (threadIdx.x < 16) {
        int s = sdata[threadIdx.x];
        #pragma unroll
        for (int o = 1; o < 16; o <<= 1) s += __shfl_xor(s, o);
        if (threadIdx.x == 0) bsum[y * nb + blockIdx.x] = s;
    }
}

// ---------------- phase B: exclusive scan of block sums (nb <= 64) ----------------
// grid 2 x 64; also writes offs[n] = total.
__global__ void scan_bsums_k(int* __restrict__ bsum, int nb, int n,
                             int* __restrict__ offs_all) {
    int y = blockIdx.x;
    int t = threadIdx.x;                 // 64 threads
    int orig = (t < nb) ? bsum[y * nb + t] : 0;
    int v = orig;
    #pragma unroll
    for (int o = 1; o < 64; o <<= 1) {
        int u = __shfl_up(v, o);
        if (t >= o) v += u;
    }
    if (t < nb) bsum[y * nb + t] = v - orig;        // exclusive base per block
    if (t == 63) offs_all[(size_t)y * (n + 1) + n] = v;  // total = E
}

// ---------------- phase C: block exclusive scan + base -> offs/cur ----------------
__global__ __launch_bounds__(1024) void scan_final_k(
        const int* __restrict__ cnt_all, int n, const int* __restrict__ bsum, int nb,
        int* __restrict__ offs_all, int* __restrict__ cur_all) {
    int y = blockIdx.y;
    const int* cnt = cnt_all + (size_t)y * n;
    int* offs = offs_all + (size_t)y * (n + 1);
    int* cur  = cur_all  + (size_t)y * n;
    int i = blockIdx.x * 1024 + threadIdx.x;
    int v = (i < n) ? cnt[i] : 0;
    __shared__ int ls[1024];
    ls[threadIdx.x] = v;
    __syncthreads();
    for (int o = 1; o < 1024; o <<= 1) {
        int u = (threadIdx.x >= o) ? ls[threadIdx.x - o] : 0;
        __syncthreads();
        ls[threadIdx.x] += u;
        __syncthreads();
    }
    if (i < n) {
        int e = bsum[y * nb + blockIdx.x] + ls[threadIdx.x] - v;  // exclusive
        offs[i] = e;
        cur[i]  = e;
    }
}

// ---------------- fill CSR col lists, pos+neg fused ----------------
__global__ void fill_k(const int* __restrict__ rows_p, const int* __restrict__ cols_p,
                       const int* __restrict__ rows_n, const int* __restrict__ cols_n,
                       int E, int* __restrict__ cur_p, int* __restrict__ cur_n,
                       int* __restrict__ coll_p, int* __restrict__ coll_n) {
    int y = blockIdx.y;
    const int* rows = y ? rows_n : rows_p;
    const int* cols = y ? cols_n : cols_p;
    int* cur = y ? cur_n : cur_p;
    int* col_list = y ? coll_n : coll_p;
    int e = blockIdx.x * blockDim.x + threadIdx.x;
    if (e < E) {
        int r = rows[e];
        int p = atomicAdd(&cur[r], 1);
        col_list[p] = cols[e];
    }
}

// ---------------- fused pos+neg CSR gather-mean from X (blockIdx.y selects) ----------------
// wave per row, lane = dim; unroll 8 -> 8 independent row loads in flight.
__global__ __launch_bounds__(256) void gatherX_k(
        const float* __restrict__ X,
        const int* __restrict__ offs_p, const int* __restrict__ col_p,
        const int* __restrict__ offs_n, const int* __restrict__ col_n,
        float* __restrict__ a1, float* __restrict__ a2, int n) {
    int y = blockIdx.y;
    const int* offs = y ? offs_n : offs_p;
    const int* cols = y ? col_n : col_p;
    float* o = y ? a2 : a1;
    int gid  = (blockIdx.x * blockDim.x + threadIdx.x) >> 6;
    int lane = threadIdx.x & 63;
    if (gid >= n) return;
    int beg = offs[gid], end = offs[gid + 1];
    float a = 0.f;
    int e = beg;
    for (; e + 7 < end; e += 8) {
        int c0 = cols[e],     c1 = cols[e + 1], c2 = cols[e + 2], c3 = cols[e + 3];
        int c4 = cols[e + 4], c5 = cols[e + 5], c6 = cols[e + 6], c7 = cols[e + 7];
        float v0 = X[(size_t)c0 * DFEAT + lane];
        float v1 = X[(size_t)c1 * DFEAT + lane];
        float v2 = X[(size_t)c2 * DFEAT + lane];
        float v3 = X[(size_t)c3 * DFEAT + lane];
        float v4 = X[(size_t)c4 * DFEAT + lane];
        float v5 = X[(size_t)c5 * DFEAT + lane];
        float v6 = X[(size_t)c6 * DFEAT + lane];
        float v7 = X[(size_t)c7 * DFEAT + lane];
        a += ((v0 + v1) + (v2 + v3)) + ((v4 + v5) + (v6 + v7));
    }
    for (; e + 3 < end; e += 4) {
        int c0 = cols[e], c1 = cols[e + 1], c2 = cols[e + 2], c3 = cols[e + 3];
        a += (X[(size_t)c0 * DFEAT + lane] + X[(size_t)c1 * DFEAT + lane])
           + (X[(size_t)c2 * DFEAT + lane] + X[(size_t)c3 * DFEAT + lane]);
    }
    for (; e < end; ++e) a += X[(size_t)cols[e] * DFEAT + lane];
    int deg = end - beg;
    o[(size_t)gid * DFEAT + lane] = a / (float)(deg > 1 ? deg : 1);
}

// ---------------- fused pos+neg dual gather-mean from hcat[n][128] ----------------
// lane l holds dims (2l, 2l+1); lanes 0-31 = h_pos half -> o1, lanes 32-63 = h_neg half -> o2.
// unroll 8 -> 8 independent 512B row loads in flight per wave.
__global__ __launch_bounds__(256) void dual_gather_k(
        const float* __restrict__ hcat,
        const int* __restrict__ offs_p, const int* __restrict__ col_p,
        const int* __restrict__ offs_n, const int* __restrict__ col_n,
        float* __restrict__ a1, float* __restrict__ a2,
        float* __restrict__ z, int n) {
    int y = blockIdx.y;
    const int* offs = y ? offs_n : offs_p;
    const int* cols = y ? col_n : col_p;
    float* o1 = y ? (z + 64) : a1;  int os1 = y ? 128 : 64;
    float* o2 = y ? z        : a2;  int os2 = y ? 128 : 64;

    int gid  = (blockIdx.x * blockDim.x + threadIdx.x) >> 6;
    int lane = threadIdx.x & 63;
    if (gid >= n) return;
    int beg = offs[gid], end = offs[gid + 1];
    float sx = 0.f, sy = 0.f;
    int e = beg;
    for (; e + 7 < end; e += 8) {
        int c0 = cols[e],     c1 = cols[e + 1], c2 = cols[e + 2], c3 = cols[e + 3];
        int c4 = cols[e + 4], c5 = cols[e + 5], c6 = cols[e + 6], c7 = cols[e + 7];
        float2 v0 = *reinterpret_cast<const float2*>(hcat + (size_t)c0 * 128 + lane * 2);
        float2 v1 = *reinterpret_cast<const float2*>(hcat + (size_t)c1 * 128 + lane * 2);
        float2 v2 = *reinterpret_cast<const float2*>(hcat + (size_t)c2 * 128 + lane * 2);
        float2 v3 = *reinterpret_cast<const float2*>(hcat + (size_t)c3 * 128 + lane * 2);
        float2 v4 = *reinterpret_cast<const float2*>(hcat + (size_t)c4 * 128 + lane * 2);
        float2 v5 = *reinterpret_cast<const float2*>(hcat + (size_t)c5 * 128 + lane * 2);
        float2 v6 = *reinterpret_cast<const float2*>(hcat + (size_t)c6 * 128 + lane * 2);
        float2 v7 = *reinterpret_cast<const float2*>(hcat + (size_t)c7 * 128 + lane * 2);
        sx += ((v0.x + v1.x) + (v2.x + v3.x)) + ((v4.x + v5.x) + (v6.x + v7.x));
        sy += ((v0.y + v1.y) + (v2.y + v3.y)) + ((v4.y + v5.y) + (v6.y + v7.y));
    }
    for (; e + 3 < end; e += 4) {
        int c0 = cols[e], c1 = cols[e + 1], c2 = cols[e + 2], c3 = cols[e + 3];
        float2 v0 = *reinterpret_cast<const float2*>(hcat + (size_t)c0 * 128 + lane * 2);
        float2 v1 = *reinterpret_cast<const float2*>(hcat + (size_t)c1 * 128 + lane * 2);
        float2 v2 = *reinterpret_cast<const float2*>(hcat + (size_t)c2 * 128 + lane * 2);
        float2 v3 = *reinterpret_cast<const float2*>(hcat + (size_t)c3 * 128 + lane * 2);
        sx += (v0.x + v1.x) + (v2.x + v3.x);
        sy += (v0.y + v1.y) + (v2.y + v3.y);
    }
    for (; e < end; ++e) {
        float2 v = *reinterpret_cast<const float2*>(hcat + (size_t)cols[e] * 128 + lane * 2);
        sx += v.x; sy += v.y;
    }
    int deg = end - beg;
    float inv = 1.f / (float)(deg > 1 ? deg : 1);
    sx *= inv; sy *= inv;
    if (lane < 32) {
        o1[(size_t)gid * os1 + lane * 2]     = sx;
        o1[(size_t)gid * os1 + lane * 2 + 1] = sy;
    } else {
        o2[(size_t)gid * os2 + (lane - 32) * 2]     = sx;
        o2[(size_t)gid * os2 + (lane - 32) * 2 + 1] = sy;
    }
}

// ---------------- fused: out = tanh(l2norm(concat @ W + b)) ----------------
template<int K, bool HAS2>
__global__ __launch_bounds__(256) void fused_linear_k(
        const float* __restrict__ p1, int s1,
        const float* __restrict__ p2, int s2,
        const float* __restrict__ p3, int s3,
        const float* __restrict__ W, const float* __restrict__ b,
        float* __restrict__ out, int os) {
    __shared__ float Ws[K * 64];
    __shared__ float bs[64];
    __shared__ float cat[4][K];

    for (int idx = threadIdx.x; idx < K * 64; idx += 256) Ws[idx] = W[idx];
    if (threadIdx.x < 64) bs[threadIdx.x] = b[threadIdx.x];

    int wave = threadIdx.x >> 6;
    int lane = threadIdx.x & 63;
    int row  = blockIdx.x * 4 + wave;      // grid sized exactly: n % 4 == 0

    cat[wave][lane] = p1[(size_t)row * s1 + lane];
    if (HAS2) {
        cat[wave][64 + lane]  = p2[(size_t)row * s2 + lane];
        cat[wave][128 + lane] = p3[(size_t)row * s3 + lane];
    } else {
        cat[wave][64 + lane]  = p3[(size_t)row * s3 + lane];
    }
    __syncthreads();

    float acc = 0.f;
    #pragma unroll
    for (int k = 0; k < K; k += 4) {
        float4 cv = *reinterpret_cast<const float4*>(&cat[wave][k]);  // broadcast
        acc = fmaf(cv.x, Ws[(k + 0) * 64 + lane], acc);
        acc = fmaf(cv.y, Ws[(k + 1) * 64 + lane], acc);
        acc = fmaf(cv.z, Ws[(k + 2) * 64 + lane], acc);
        acc = fmaf(cv.w, Ws[(k + 3) * 64 + lane], acc);
    }
    float v = acc + bs[lane];
    float ss = v * v;
    #pragma unroll
    for (int i = 1; i < 64; i <<= 1) ss += __shfl_xor(ss, i);
    float denom = fmaxf(sqrtf(ss), 1e-12f);
    out[(size_t)row * os + lane] = tanhf(v / denom);
}

// ---------------- normalize z rows -> bf16 table zn[n][128] ----------------
__global__ __launch_bounds__(256) void normalize_k(
        const float* __restrict__ z, u16* __restrict__ zn, int n) {
    int gid  = (blockIdx.x * blockDim.x + threadIdx.x) >> 6;
    int lane = threadIdx.x & 63;
    if (gid >= n) return;
    float v0 = z[(size_t)gid * 128 + lane * 2];
    float v1 = z[(size_t)gid * 128 + lane * 2 + 1];
    float ss = v0 * v0 + v1 * v1;
    #pragma unroll
    for (int o = 1; o < 64; o <<= 1) ss += __shfl_xor(ss, o);
    float inv = 1.f / fmaxf(sqrtf(ss), 1e-8f);
    __hip_bfloat16 b0 = __float2bfloat16(v0 * inv);
    __hip_bfloat16 b1 = __float2bfloat16(v1 * inv);
    u16 s0 = *reinterpret_cast<u16*>(&b0);
    u16 s1 = *reinterpret_cast<u16*>(&b1);
    u32 packed = (u32)s0 | ((u32)s1 << 16);
    *reinterpret_cast<u32*>(zn + (size_t)gid * 128 + lane * 2) = packed;
}

// ---------------- logits + log_softmax + argmax ----------------
__global__ __launch_bounds__(256) void logits_k(
        const float* __restrict__ z, const float* __restrict__ Wr,
        const float* __restrict__ br, const int* __restrict__ comm,
        float* __restrict__ clar_f, int* __restrict__ clar_i,
        float* __restrict__ lp_sum, int n) {
    __shared__ float Wl[128 * 3];
    for (int idx = threadIdx.x; idx < 384; idx += blockDim.x) Wl[idx] = Wr[idx];
    __syncthreads();
    int i = blockIdx.x * blockDim.x + threadIdx.x;
    float lp = 0.f;
    if (i < n) {
        float l0 = br[0], l1 = br[1], l2 = br[2];
        const float* zr = z + (size_t)i * 128;
        #pragma unroll 4
        for (int k = 0; k < 128; k += 4) {
            float4 v = *reinterpret_cast<const float4*>(zr + k);
            float zz[4] = {v.x, v.y, v.z, v.w};
            #pragma unroll
            for (int j = 0; j < 4; ++j) {
                float zv = zz[j];
                int kk = k + j;
                l0 = fmaf(zv, Wl[3 * kk + 0], l0);
                l1 = fmaf(zv, Wl[3 * kk + 1], l1);
                l2 = fmaf(zv, Wl[3 * kk + 2], l2);
            }
        }
        int idx = 0; float mv = l0;
        if (l1 > mv) { mv = l1; idx = 1; }
        if (l2 > mv) { mv = l2; idx = 2; }
        clar_i[i] = idx;
        clar_f[i] = (float)idx;
        float lse = mv + logf(expf(l0 - mv) + expf(l1 - mv) + expf(l2 - mv));
        int c = comm[i];
        lp = (c == 0 ? l0 : (c == 1 ? l1 : l2)) - lse;
    }
    #pragma unroll
    for (int o = 1; o < 64; o <<= 1) lp += __shfl_xor(lp, o);
    __shared__ float wsum[4];
    if ((threadIdx.x & 63) == 0) wsum[threadIdx.x >> 6] = lp;
    __syncthreads();
    if (threadIdx.x == 0) atomicAdd(lp_sum, wsum[0] + wsum[1] + wsum[2] + wsum[3]);
}

// ---------------- CSR-row-grouped cosine-sim losses, GRID-STRIDED ----------------
// Fixed grid (1024 blocks x 2 modes) -> 2048 total atomics (per-block atomicAdd
// to ONE address serializes at ~14ns; block count must stay small). One wave per
// row per iteration: zn[a] in regs, clar pre-check skips the 256B row load.
__global__ __launch_bounds__(256) void sim_rows_k(
        const u16* __restrict__ zn, const int* __restrict__ clar,
        const int* __restrict__ offs_p, const int* __restrict__ col_p,
        const int* __restrict__ offs_n, const int* __restrict__ col_n,
        float* __restrict__ scal, int n) {
    int mode = blockIdx.y;
    const int* offs = mode ? offs_n : offs_p;
    const int* cols = mode ? col_n : col_p;
    int lane = threadIdx.x & 63;
    int sub  = lane & 15;
    int q    = lane >> 4;
    int wid    = blockIdx.x * 4 + (threadIdx.x >> 6);
    int nwaves = gridDim.x * 4;
    float total = 0.f;
    for (int gid = wid; gid < n; gid += nwaves) {
        uint4 ua = *reinterpret_cast<const uint4*>(zn + (size_t)gid * 128 + sub * 8);
        float a0 = bflo(ua.x), a1 = bfhi(ua.x), a2 = bflo(ua.y), a3 = bfhi(ua.y);
        float a4 = bflo(ua.z), a5 = bfhi(ua.z), a6 = bflo(ua.w), a7 = bfhi(ua.w);
        int ca = clar[gid];
        int beg = offs[gid], end = offs[gid + 1];
        #pragma unroll 2
        for (int e = beg + q; e < end; e += 4) {
            int b = cols[e];
            int cb = clar[b];                 // L2-hot 200KB table, checked pre-load
            bool sel = mode ? (cb == ca) : (cb != ca);
            if (sel) {
                uint4 ub = *reinterpret_cast<const uint4*>(zn + (size_t)b * 128 + sub * 8);
                float d;
                d = a0 * bflo(ub.x);
                d = fmaf(a1, bfhi(ub.x), d);
                d = fmaf(a2, bflo(ub.y), d);
                d = fmaf(a3, bfhi(ub.y), d);
                d = fmaf(a4, bflo(ub.z), d);
                d = fmaf(a5, bfhi(ub.z), d);
                d = fmaf(a6, bflo(ub.w), d);
                d = fmaf(a7, bfhi(ub.w), d);
                d += __shfl_xor(d, 1);
                d += __shfl_xor(d, 2);
                d += __shfl_xor(d, 4);
                d += __shfl_xor(d, 8);
                if (sub == 0) total += mode ? -fminf(d, 0.f) : fmaxf(d, 0.f);
            }
        }
    }
    // non-sub0 lanes hold 0; full 64-lane reduce then one atomic per block
    #pragma unroll
    for (int o = 1; o < 64; o <<= 1) total += __shfl_xor(total, o);
    __shared__ float wsum[4];
    if ((threadIdx.x & 63) == 0) wsum[threadIdx.x >> 6] = total;
    __syncthreads();
    if (threadIdx.x == 0) atomicAdd(&scal[1 + mode], wsum[0] + wsum[1] + wsum[2] + wsum[3]);
}

__global__ void finalize_k(const float* __restrict__ scal, float* __restrict__ out,
                           int n, int E) {
    if (threadIdx.x == 0 && blockIdx.x == 0) {
        float reg_loss = -scal[0] / (float)n;
        float sim1 = scal[1] / (float)E;
        float sim2 = scal[2] / (float)E;
        out[0] = 0.8f * reg_loss + 0.2f * (sim1 + sim2);
    }
}

extern "C" void kernel_launch(void* const* d_in, const int* in_sizes, int n_in,
                              void* d_out, int out_size, void* d_ws, size_t ws_size,
                              hipStream_t stream) {
    const float* X   = (const float*)d_in[0];
    const float* pbW = (const float*)d_in[1];
    const float* pbB = (const float*)d_in[2];
    const float* nbW = (const float*)d_in[3];
    const float* nbB = (const float*)d_in[4];
    const float* pdW = (const float*)d_in[5];
    const float* pdB = (const float*)d_in[6];
    const float* ndW = (const float*)d_in[7];
    const float* ndB = (const float*)d_in[8];
    const float* rW  = (const float*)d_in[9];
    const float* rB  = (const float*)d_in[10];
    const int* pe    = (const int*)d_in[11];
    const int* ne    = (const int*)d_in[12];
    const int* comm  = (const int*)d_in[13];

    const int E = in_sizes[11] / 2;          // 800000
    const int n = in_sizes[0] / DFEAT;       // 50000

    float* out    = (float*)d_out;
    float* z      = out + 1;                             // [n,128]
    float* clar_f = out + 1 + (size_t)n * 128;           // [n]

    // workspace layout
    char*  w   = (char*)d_ws;
    size_t big = (size_t)n * DFEAT * sizeof(float);      // 12.8 MB
    float* a1    = (float*)(w);                          // [n,64]; later zn (bf16 [n,128])
    float* a2    = (float*)(w + big);                    // [n,64]
    float* hcat  = (float*)(w + 2 * big);                // [n,128] = h_pos | h_neg
    u16*   zn    = (u16*)a1;                             // n*128*2B == big exactly
    char*  sm    = w + 4 * big;
    int* col_p  = (int*)sm;  sm += (size_t)E * 4;
    int* col_n  = (int*)sm;  sm += (size_t)E * 4;
    int* offs   = (int*)sm;  sm += 2 * (size_t)(n + 1) * 4;  // offs_p | offs_n
    int* cur    = (int*)sm;  sm += 2 * (size_t)n * 4;        // cur_p | cur_n
    int* cnt    = (int*)sm;  sm += 2 * (size_t)n * 4;        // cnt_p | cnt_n
    int* clar_i = (int*)sm;  sm += (size_t)n * 4;
    int* bsum   = (int*)sm;  sm += 2 * 64 * 4;               // block sums for scan
    float* scal = (float*)sm; sm += 64;   // [0]=lp_sum [1]=sim1 [2]=sim2

    int* offs_p = offs;
    int* offs_n = offs + (n + 1);
    int* cur_p  = cur;
    int* cur_n  = cur + n;
    int* cnt_p  = cnt;
    int* cnt_n  = cnt + n;

    const int* rp = pe, *cp = pe + E;
    const int* rn = ne, *cn = ne + E;

    const int egrid = (E + 255) / 256;
    const int ngrid = (n + 255) / 256;
    const int fgrid = n / 4;                 // n % 4 == 0 (12500)
    const int nb    = (n + 1023) / 1024;     // 49 scan blocks per edge-type

    // zero only small accumulators (ws is poisoned each call)
    hipMemsetAsync(cnt, 0, 2 * (size_t)n * 4, stream);
    hipMemsetAsync(scal, 0, 64, stream);

    // ---- CSR build (pos & neg), reused by all aggregations + sims ----
    count_edges_k<<<dim3(egrid, 2), 256, 0, stream>>>(rp, rn, E, cnt_p, cnt_n);
    scan_partial_k<<<dim3(nb, 2), 1024, 0, stream>>>(cnt, n, bsum, nb);
    scan_bsums_k<<<2, 64, 0, stream>>>(bsum, nb, n, offs);
    scan_final_k<<<dim3(nb, 2), 1024, 0, stream>>>(cnt, n, bsum, nb, offs, cur);
    fill_k<<<dim3(egrid, 2), 256, 0, stream>>>(rp, cp, rn, cn, E, cur_p, cur_n, col_p, col_n);

    // ---- layer 0 (base): both CSR gathers in one dispatch ----
    gatherX_k<<<dim3(fgrid, 2), 256, 0, stream>>>(X, offs_p, col_p, offs_n, col_n, a1, a2, n);
    // h_pos -> hcat[:, 0:64], h_neg -> hcat[:, 64:128]
    fused_linear_k<128, false><<<fgrid, 256, 0, stream>>>(a1, 64, nullptr, 0, X, 64, pbW, pbB, hcat, 128);
    fused_linear_k<128, false><<<fgrid, 256, 0, stream>>>(a2, 64, nullptr, 0, X, 64, nbW, nbB, hcat + 64, 128);

    // ---- deep-layer aggregations: both CSRs in one dispatch ----
    // y=0 (pos-CSR): mean h_pos -> a1, mean h_neg -> a2
    // y=1 (neg-CSR): mean h_pos -> z[:,64:], mean h_neg -> z[:,:64]
    dual_gather_k<<<dim3(fgrid, 2), 256, 0, stream>>>(hcat, offs_p, col_p, offs_n, col_n, a1, a2, z, n);

    // ---- deep linears (p2 in-place per-row with out: safe, per-row reads precede write) ----
    fused_linear_k<192, true><<<fgrid, 256, 0, stream>>>(a1, 64, z, 128, hcat, 128, pdW, pdB, z, 128);
    fused_linear_k<192, true><<<fgrid, 256, 0, stream>>>(a2, 64, z + 64, 128, hcat + 64, 128, ndW, ndB, z + 64, 128);

    // ---- normalized bf16 z table (overwrites a1 — free now) ----
    normalize_k<<<fgrid, 256, 0, stream>>>(z, zn, n);

    // ---- losses ----
    logits_k<<<ngrid, 256, 0, stream>>>(z, rW, rB, comm, clar_f, clar_i, &scal[0], n);
    sim_rows_k<<<dim3(1024, 2), 256, 0, stream>>>(zn, clar_i, offs_p, col_p, offs_n, col_n, scal, n);
    finalize_k<<<1, 64, 0, stream>>>(scal, out, n, E);
}